// Round 1
// baseline (1703.075 us; speedup 1.0000x reference)
//
#include <hip/hip_runtime.h>
#include <hip/hip_bf16.h>

// Problem constants (from reference): B=64, NCLS=200 -> BN rows = 12800
#define BROWS  12800
#define TSTEPS 8
#define EMB    300
#define EMBP   320          // EMB padded to /32 for MFMA K
#define RNN    512
#define NG     2048         // 4*RNN gate width
#define K1     832          // EMBP + RNN  (layer-1 concat GEMM K), 13*64
#define K2     1024         // RNN + RNN   (layer-2 concat GEMM K), 16*64

typedef short bf16x8 __attribute__((ext_vector_type(8)));   // 8 bf16 in 4 VGPRs (m89-verified operand type)
typedef float f32x4  __attribute__((ext_vector_type(4)));
typedef __hip_bfloat16 bf16;

__device__ __forceinline__ float sigmoidf_(float x) { return 1.f / (1.f + __expf(-x)); }

// ---------------------------------------------------------------------------
// Weight repack: fp32 -> bf16, K-concatenated row-major [N=2048][K]
// Wc1[n][k]: k<300 = W_ih1[n][k]; 300..319 = 0 (pad); k>=320 = W_hh1[n][k-320]
// Wc2[n][k]: k<512 = W_ih2[n][k]; k>=512 = W_hh2[n][k-512]
// ---------------------------------------------------------------------------
__global__ void convert_weights(const float* __restrict__ Wih1, const float* __restrict__ Whh1,
                                const float* __restrict__ Wih2, const float* __restrict__ Whh2,
                                bf16* __restrict__ Wc1, bf16* __restrict__ Wc2) {
    int idx = blockIdx.x * 256 + threadIdx.x;
    const int n1 = NG * K1;   // 1,703,936
    const int n2 = NG * K2;   // 2,097,152
    if (idx < n1) {
        int n = idx / K1, k = idx - n * K1;
        float v = 0.f;
        if (k < EMB)        v = Wih1[n * EMB + k];
        else if (k >= EMBP) v = Whh1[n * RNN + (k - EMBP)];
        Wc1[idx] = __float2bfloat16(v);
    }
    if (idx < n2) {
        int n = idx >> 10, k = idx & (K2 - 1);
        float v = (k < RNN) ? Wih2[n * RNN + k] : Whh2[n * RNN + (k - RNN)];
        Wc2[idx] = __float2bfloat16(v);
    }
}

// ---------------------------------------------------------------------------
// Embedding gather + tanh for one timestep, written into the x-slot (cols
// 0..319, pad cols zeroed) of the layer-1 A-concat buffer Ac1 [BROWS][K1].
// One block per row, 320 threads (5 waves); lanes of a row read contiguous
// w2v columns -> coalesced; w2v (24 MB) lives in L3 after first touch.
// ---------------------------------------------------------------------------
__global__ void embed_step(const int* __restrict__ sent, const float* __restrict__ w2v,
                           bf16* __restrict__ Ac1, int t) {
    int row = blockIdx.x;
    int col = threadIdx.x;                 // 0..319
    int id  = sent[row * TSTEPS + t];
    float v = (col < EMB) ? tanhf(w2v[id * EMB + col]) : 0.f;
    Ac1[(size_t)row * K1 + col] = __float2bfloat16(v);
}

// ---------------------------------------------------------------------------
// C[M,2048] (fp32) = A[M,K] * B[2048,K]^T, bf16 inputs, MFMA 16x16x32.
// Block: 256 thr = 4 waves; tile 128x128; each wave 64x64 (4x4 MFMA tiles).
// LDS row stride 72 bf16 (=144B -> rows shift 4 banks -> 2-way aliasing only,
// which is free on gfx950 per m136). M,N,K all exact multiples of tile dims.
// ---------------------------------------------------------------------------
#define BM 128
#define BN 128
#define BK 64
#define LDK 72

__global__ __launch_bounds__(256, 2) void gemm_btn(const bf16* __restrict__ A,
                                                   const bf16* __restrict__ B,
                                                   float* __restrict__ C,
                                                   int K) {
    __shared__ __attribute__((aligned(16))) bf16 sA[BM][LDK];
    __shared__ __attribute__((aligned(16))) bf16 sB[BN][LDK];

    const int tid  = threadIdx.x;
    const int lane = tid & 63;
    const int wave = tid >> 6;
    const int wm   = wave >> 1, wn = wave & 1;
    const int bm   = blockIdx.x;           // M/128
    const int bn   = blockIdx.y;           // 16

    f32x4 acc[4][4];
#pragma unroll
    for (int i = 0; i < 4; ++i)
#pragma unroll
        for (int j = 0; j < 4; ++j)
#pragma unroll
            for (int r = 0; r < 4; ++r) acc[i][j][r] = 0.f;

    const int r = lane & 15, q = lane >> 4;

    for (int kb = 0; kb < K; kb += BK) {
        // stage 128x64 bf16 tiles of A and B: 1024 16B-chunks each, 4/thread
#pragma unroll
        for (int c = 0; c < 4; ++c) {
            int chunk = tid + c * 256;
            int row = chunk >> 3, kg = chunk & 7;
            *(uint4*)(&sA[row][kg * 8]) =
                *(const uint4*)(A + (size_t)(bm * BM + row) * K + kb + kg * 8);
            *(uint4*)(&sB[row][kg * 8]) =
                *(const uint4*)(B + (size_t)(bn * BN + row) * K + kb + kg * 8);
        }
        __syncthreads();
#pragma unroll
        for (int kk = 0; kk < BK; kk += 32) {
            bf16x8 af[4], bfr[4];
#pragma unroll
            for (int i = 0; i < 4; ++i)
                af[i] = *(const bf16x8*)(&sA[wm * 64 + i * 16 + r][kk + q * 8]);
#pragma unroll
            for (int j = 0; j < 4; ++j)
                bfr[j] = *(const bf16x8*)(&sB[wn * 64 + j * 16 + r][kk + q * 8]);
#pragma unroll
            for (int i = 0; i < 4; ++i)
#pragma unroll
                for (int j = 0; j < 4; ++j)
                    acc[i][j] = __builtin_amdgcn_mfma_f32_16x16x32_bf16(
                        af[i], bfr[j], acc[i][j], 0, 0, 0);
        }
        __syncthreads();
    }

    // C/D mapping (m89/m91-verified): col = lane&15, row = (lane>>4)*4 + reg
#pragma unroll
    for (int i = 0; i < 4; ++i)
#pragma unroll
        for (int j = 0; j < 4; ++j) {
            int col = bn * BN + wn * 64 + j * 16 + r;
#pragma unroll
            for (int rr = 0; rr < 4; ++rr) {
                int rowg = bm * BM + wm * 64 + i * 16 + q * 4 + rr;
                C[(size_t)rowg * NG + col] = acc[i][j][rr];
            }
        }
}

// ---------------------------------------------------------------------------
// LSTM cell pointwise update. gates G[row][gate*512+j] (i,f,g,o order),
// biases added here (kept fp32). c state fp32 in/out. h written as bf16 into
// up to two strided A-buffer slots (next-step inputs); optionally fp32 to out.
// ---------------------------------------------------------------------------
__global__ void lstm_update(const float* __restrict__ G,
                            const float* __restrict__ bih, const float* __restrict__ bhh,
                            float* __restrict__ c,
                            bf16* __restrict__ hdst1, int ld1, int off1, int en1,
                            bf16* __restrict__ hdst2, int ld2, int off2, int en2,
                            float* __restrict__ outf, int en_out) {
    int idx = blockIdx.x * 256 + threadIdx.x;      // BROWS*RNN
    int row = idx >> 9, j = idx & (RNN - 1);
    size_t base = (size_t)row * NG;
    float gi = G[base + j]            + bih[j]            + bhh[j];
    float gf = G[base + RNN + j]      + bih[RNN + j]      + bhh[RNN + j];
    float gg = G[base + 2 * RNN + j]  + bih[2 * RNN + j]  + bhh[2 * RNN + j];
    float go = G[base + 3 * RNN + j]  + bih[3 * RNN + j]  + bhh[3 * RNN + j];
    float cn = sigmoidf_(gf) * c[idx] + sigmoidf_(gi) * tanhf(gg);
    float h  = sigmoidf_(go) * tanhf(cn);
    c[idx] = cn;
    bf16 hb = __float2bfloat16(h);
    if (en1) hdst1[(size_t)row * ld1 + off1 + j] = hb;
    if (en2) hdst2[(size_t)row * ld2 + off2 + j] = hb;
    if (en_out) outf[idx] = h;
}

// ---------------------------------------------------------------------------
// Workspace layout (all 16B-aligned; total 212,402,176 B):
//   c1  fp32 [12800][512]            26,214,400
//   c2  fp32 [12800][512]            26,214,400
//   A2  bf16 [12800][1024]           26,214,400   ([h1|h2] for layer-2 GEMM)
//   Ac1 bf16 [12800][832]            21,299,200   ([x_t(pad)|h1] for layer-1)
//   Wc1 bf16 [2048][832]              3,407,872
//   Wc2 bf16 [2048][1024]             4,194,304
//   G   fp32 [12800][2048]          104,857,600   (gates scratch)
// First 99,942,400 B (c1,c2,A2,Ac1) must be zero at t=0 -> one memsetAsync.
// ---------------------------------------------------------------------------
extern "C" void kernel_launch(void* const* d_in, const int* in_sizes, int n_in,
                              void* d_out, int out_size, void* d_ws, size_t ws_size,
                              hipStream_t stream) {
    (void)in_sizes; (void)n_in; (void)out_size; (void)ws_size;
    const int*   sent = (const int*)d_in[0];
    const float* w2v  = (const float*)d_in[1];
    const float* Wih1 = (const float*)d_in[2];
    const float* Whh1 = (const float*)d_in[3];
    const float* bih1 = (const float*)d_in[4];
    const float* bhh1 = (const float*)d_in[5];
    const float* Wih2 = (const float*)d_in[6];
    const float* Whh2 = (const float*)d_in[7];
    const float* bih2 = (const float*)d_in[8];
    const float* bhh2 = (const float*)d_in[9];
    float* out = (float*)d_out;

    char* ws = (char*)d_ws;
    float* c1  = (float*)(ws);
    float* c2  = (float*)(ws + 26214400);
    bf16*  A2  = (bf16*) (ws + 52428800);
    bf16*  Ac1 = (bf16*) (ws + 78643200);
    bf16*  Wc1 = (bf16*) (ws + 99942400);
    bf16*  Wc2 = (bf16*) (ws + 103350272);
    float* G   = (float*)(ws + 107544576);

    // zero h/c state + A-buffers (ws is re-poisoned 0xAA before every call)
    hipMemsetAsync(ws, 0, 99942400, stream);

    convert_weights<<<dim3((NG * K2 + 255) / 256), dim3(256), 0, stream>>>(
        Wih1, Whh1, Wih2, Whh2, Wc1, Wc2);

    for (int t = 0; t < TSTEPS; ++t) {
        // x_t -> Ac1 cols [0,320); h1(t-1) already sits in cols [320,832)
        embed_step<<<dim3(BROWS), dim3(EMBP), 0, stream>>>(sent, w2v, Ac1, t);

        // gates1 = [x_t|h1] @ [W_ih1|W_hh1]^T
        gemm_btn<<<dim3(BROWS / BM, NG / BN), dim3(256), 0, stream>>>(Ac1, Wc1, G, K1);
        // h1,c1 update; h1 -> Ac1 h-slot (next step) and A2 cols [0,512)
        lstm_update<<<dim3(BROWS * RNN / 256), dim3(256), 0, stream>>>(
            G, bih1, bhh1, c1,
            Ac1, K1, EMBP, 1,
            A2,  K2, 0,    1,
            (float*)nullptr, 0);

        // gates2 = [h1|h2] @ [W_ih2|W_hh2]^T
        gemm_btn<<<dim3(BROWS / BM, NG / BN), dim3(256), 0, stream>>>(A2, Wc2, G, K2);
        // h2,c2 update; h2 -> A2 cols [512,1024) (next step); final step -> out
        lstm_update<<<dim3(BROWS * RNN / 256), dim3(256), 0, stream>>>(
            G, bih2, bhh2, c2,
            A2, K2, RNN, 1,
            (bf16*)nullptr, 0, 0, 0,
            out, (t == TSTEPS - 1) ? 1 : 0);
    }
}

// Round 2
// 1362.511 us; speedup vs baseline: 1.2500x; 1.2500x over previous
//
#include <hip/hip_runtime.h>
#include <hip/hip_bf16.h>

// Problem constants (from reference): B=64, NCLS=200 -> BN rows = 12800
#define BROWS  12800
#define TSTEPS 8
#define EMB    300
#define EMBP   320          // EMB padded to /32 for MFMA K
#define RNN    512
#define NG     2048         // 4*RNN gate width
#define K1     832          // EMBP + RNN  (layer-1 concat GEMM K), 13*64
#define K2     1024         // RNN + RNN   (layer-2 concat GEMM K), 16*64

typedef short bf16x8 __attribute__((ext_vector_type(8)));   // 8 bf16 in 4 VGPRs (m89-verified operand type)
typedef float f32x4  __attribute__((ext_vector_type(4)));
typedef __hip_bfloat16 bf16;

__device__ __forceinline__ float sigmoidf_(float x) { return 1.f / (1.f + __expf(-x)); }
// exp-based tanh: exact at +-inf saturation, ~ulp-level error vs tanhf, one v_exp
__device__ __forceinline__ float tanhf_(float x)    { return 1.f - 2.f / (__expf(2.f * x) + 1.f); }

// ---------------------------------------------------------------------------
// Weight repack: fp32 -> bf16, K-concatenated row-major [N=2048][K], with the
// GATE-INTERLEAVED row permutation: output row n encodes
//   w = n&15 (unit within 16-group), g = (n>>4)&3 (gate i,f,g,o), b = n>>6
//   original row = g*512 + b*16 + w
// so each 64-col span = [i|f|g|o] of units 16b..16b+15 -> a single wave's
// 4 j-tiles hold all four gates of the SAME 16 units (epilogue needs no
// cross-lane exchange). Also emits permuted combined biases Bp = bih+bhh.
// ---------------------------------------------------------------------------
__global__ void convert_weights(const float* __restrict__ Wih1, const float* __restrict__ Whh1,
                                const float* __restrict__ Wih2, const float* __restrict__ Whh2,
                                const float* __restrict__ bih1, const float* __restrict__ bhh1,
                                const float* __restrict__ bih2, const float* __restrict__ bhh2,
                                bf16* __restrict__ Wc1, bf16* __restrict__ Wc2,
                                float* __restrict__ Bp1, float* __restrict__ Bp2) {
    int idx = blockIdx.x * 256 + threadIdx.x;
    const int n1 = NG * K1;   // 1,703,936
    const int n2 = NG * K2;   // 2,097,152
    if (idx < n1) {
        int n = idx / K1, k = idx - n * K1;
        int on = ((n >> 4) & 3) * RNN + (n >> 6) * 16 + (n & 15);
        float v = 0.f;
        if (k < EMB)        v = Wih1[on * EMB + k];
        else if (k >= EMBP) v = Whh1[on * RNN + (k - EMBP)];
        Wc1[idx] = __float2bfloat16(v);
    }
    if (idx < n2) {
        int n = idx >> 10, k = idx & (K2 - 1);
        int on = ((n >> 4) & 3) * RNN + (n >> 6) * 16 + (n & 15);
        float v = (k < RNN) ? Wih2[on * RNN + k] : Whh2[on * RNN + (k - RNN)];
        Wc2[idx] = __float2bfloat16(v);
    }
    if (idx < NG) {
        int on = ((idx >> 4) & 3) * RNN + (idx >> 6) * 16 + (idx & 15);
        Bp1[idx] = bih1[on] + bhh1[on];
        Bp2[idx] = bih2[on] + bhh2[on];
    }
}

// ---------------------------------------------------------------------------
// Embedding gather + tanh for one timestep, written into the x-slot (cols
// 0..319, pad cols zeroed) of the layer-1 A-concat buffer Ac1 [BROWS][K1].
// ---------------------------------------------------------------------------
__global__ void embed_step(const int* __restrict__ sent, const float* __restrict__ w2v,
                           bf16* __restrict__ Ac1, int t) {
    int row = blockIdx.x;
    int col = threadIdx.x;                 // 0..319
    int id  = sent[row * TSTEPS + t];
    float v = (col < EMB) ? tanhf_(w2v[id * EMB + col]) : 0.f;
    Ac1[(size_t)row * K1 + col] = __float2bfloat16(v);
}

// ---------------------------------------------------------------------------
// Fused GEMM + LSTM cell update.
//   gates[M,2048] = A[M,K] * B[2048,K]^T  (bf16 MFMA 16x16x32, fp32 acc)
// then per (row, unit): c' = sig(f)*c + sig(i)*tanh(g); h = sig(o)*tanh(c')
// c updated in place (fp32); h written bf16 to up to two A-buffer slots
// (next GEMM inputs), optionally fp32 to d_out.
// Block 256 thr = 4 waves; tile 128x128; wave = 64x64 = 4x4 MFMA tiles.
// Thanks to the weight permutation, wave wn's 64 cols = units
// [(2bn+wn)*16, +16) x gates {i,f,g,o}, so acc[i][0..3][rr] are the four
// gates of one (row, unit) held by a single thread.
// LDS row stride 72 bf16 -> rows shift 4 banks -> 2-way aliasing only (free).
// Grid: (NG/BN=16, BROWS/BM=100), bn = blockIdx.x varies fastest so
// concurrent blocks share A row-tiles (L2 reuse).
// ---------------------------------------------------------------------------
#define BM 128
#define BN 128
#define BK 64
#define LDK 72

__global__ __launch_bounds__(256, 2) void gemm_lstm(const bf16* __restrict__ A,
                                                    const bf16* __restrict__ B,
                                                    const float* __restrict__ Bp,
                                                    float* __restrict__ cst,
                                                    bf16* __restrict__ hdst1, int ld1, int off1,
                                                    bf16* __restrict__ hdst2, int ld2, int off2, int en2,
                                                    float* __restrict__ outf, int en_out,
                                                    int K) {
    __shared__ __attribute__((aligned(16))) bf16 sA[BM][LDK];
    __shared__ __attribute__((aligned(16))) bf16 sB[BN][LDK];

    const int tid  = threadIdx.x;
    const int lane = tid & 63;
    const int wave = tid >> 6;
    const int wm   = wave >> 1, wn = wave & 1;
    const int bn   = blockIdx.x;           // 16  (gate-col blocks)
    const int bm   = blockIdx.y;           // 100 (row blocks)

    f32x4 acc[4][4];
#pragma unroll
    for (int i = 0; i < 4; ++i)
#pragma unroll
        for (int j = 0; j < 4; ++j)
#pragma unroll
            for (int r = 0; r < 4; ++r) acc[i][j][r] = 0.f;

    const int r = lane & 15, q = lane >> 4;

    for (int kb = 0; kb < K; kb += BK) {
        // stage 128x64 bf16 tiles of A and B: 1024 16B-chunks each, 4/thread
#pragma unroll
        for (int c = 0; c < 4; ++c) {
            int chunk = tid + c * 256;
            int row = chunk >> 3, kg = chunk & 7;
            *(uint4*)(&sA[row][kg * 8]) =
                *(const uint4*)(A + (size_t)(bm * BM + row) * K + kb + kg * 8);
            *(uint4*)(&sB[row][kg * 8]) =
                *(const uint4*)(B + (size_t)(bn * BN + row) * K + kb + kg * 8);
        }
        __syncthreads();
#pragma unroll
        for (int kk = 0; kk < BK; kk += 32) {
            bf16x8 af[4], bfr[4];
#pragma unroll
            for (int i = 0; i < 4; ++i)
                af[i] = *(const bf16x8*)(&sA[wm * 64 + i * 16 + r][kk + q * 8]);
#pragma unroll
            for (int j = 0; j < 4; ++j)
                bfr[j] = *(const bf16x8*)(&sB[wn * 64 + j * 16 + r][kk + q * 8]);
#pragma unroll
            for (int i = 0; i < 4; ++i)
#pragma unroll
                for (int j = 0; j < 4; ++j)
                    acc[i][j] = __builtin_amdgcn_mfma_f32_16x16x32_bf16(
                        af[i], bfr[j], acc[i][j], 0, 0, 0);
        }
        __syncthreads();
    }

    // ---- fused LSTM epilogue ----
    // C/D mapping (m89/m91-verified): col = lane&15, row = (lane>>4)*4 + reg
    const int colb = bn * BN + wn * 64;           // this wave's first gate col
    const int u    = (2 * bn + wn) * 16 + r;      // global unit index
    const float bi = Bp[colb + r];
    const float bf = Bp[colb + 16 + r];
    const float bg = Bp[colb + 32 + r];
    const float bo = Bp[colb + 48 + r];

#pragma unroll
    for (int i = 0; i < 4; ++i) {
#pragma unroll
        for (int rr = 0; rr < 4; ++rr) {
            int row = bm * BM + wm * 64 + i * 16 + q * 4 + rr;
            size_t cidx = (size_t)row * RNN + u;
            float gi = acc[i][0][rr] + bi;
            float gf = acc[i][1][rr] + bf;
            float gg = acc[i][2][rr] + bg;
            float go = acc[i][3][rr] + bo;
            float cn = sigmoidf_(gf) * cst[cidx] + sigmoidf_(gi) * tanhf_(gg);
            float h  = sigmoidf_(go) * tanhf_(cn);
            cst[cidx] = cn;
            bf16 hb = __float2bfloat16(h);
            hdst1[(size_t)row * ld1 + off1 + u] = hb;
            if (en2)    hdst2[(size_t)row * ld2 + off2 + u] = hb;
            if (en_out) outf[cidx] = h;
        }
    }
}

// ---------------------------------------------------------------------------
// Workspace layout (all 16B-aligned; total 107,560,960 B):
//   c1  fp32 [12800][512]            26,214,400
//   c2  fp32 [12800][512]            26,214,400
//   A2  bf16 [12800][1024]           26,214,400   ([h1|h2] for layer-2 GEMM)
//   Ac1 bf16 [12800][832]            21,299,200   ([x_t(pad)|h1] for layer-1)
//   Wc1 bf16 [2048][832]              3,407,872
//   Wc2 bf16 [2048][1024]             4,194,304
//   Bp1 fp32 [2048]                       8,192
//   Bp2 fp32 [2048]                       8,192
// First 99,942,400 B (c1,c2,A2,Ac1) must be zero at t=0 -> one memsetAsync.
// ---------------------------------------------------------------------------
extern "C" void kernel_launch(void* const* d_in, const int* in_sizes, int n_in,
                              void* d_out, int out_size, void* d_ws, size_t ws_size,
                              hipStream_t stream) {
    (void)in_sizes; (void)n_in; (void)out_size; (void)ws_size;
    const int*   sent = (const int*)d_in[0];
    const float* w2v  = (const float*)d_in[1];
    const float* Wih1 = (const float*)d_in[2];
    const float* Whh1 = (const float*)d_in[3];
    const float* bih1 = (const float*)d_in[4];
    const float* bhh1 = (const float*)d_in[5];
    const float* Wih2 = (const float*)d_in[6];
    const float* Whh2 = (const float*)d_in[7];
    const float* bih2 = (const float*)d_in[8];
    const float* bhh2 = (const float*)d_in[9];
    float* out = (float*)d_out;

    char* ws = (char*)d_ws;
    float* c1  = (float*)(ws);
    float* c2  = (float*)(ws + 26214400);
    bf16*  A2  = (bf16*) (ws + 52428800);
    bf16*  Ac1 = (bf16*) (ws + 78643200);
    bf16*  Wc1 = (bf16*) (ws + 99942400);
    bf16*  Wc2 = (bf16*) (ws + 103350272);
    float* Bp1 = (float*)(ws + 107544576);
    float* Bp2 = (float*)(ws + 107552768);

    // zero h/c state + A-buffers (ws is re-poisoned 0xAA before every call)
    hipMemsetAsync(ws, 0, 99942400, stream);

    convert_weights<<<dim3((NG * K2 + 255) / 256), dim3(256), 0, stream>>>(
        Wih1, Whh1, Wih2, Whh2, bih1, bhh1, bih2, bhh2, Wc1, Wc2, Bp1, Bp2);

    for (int t = 0; t < TSTEPS; ++t) {
        // x_t -> Ac1 cols [0,320); h1(t-1) already sits in cols [320,832)
        embed_step<<<dim3(BROWS), dim3(EMBP), 0, stream>>>(sent, w2v, Ac1, t);

        // layer 1: gates = [x_t|h1] @ Wc1^T, fused update
        // h1 -> Ac1 h-slot (next step) and A2 cols [0,512) (this step)
        gemm_lstm<<<dim3(NG / BN, BROWS / BM), dim3(256), 0, stream>>>(
            Ac1, Wc1, Bp1, c1,
            Ac1, K1, EMBP,
            A2,  K2, 0, 1,
            (float*)nullptr, 0, K1);

        // layer 2: gates = [h1|h2] @ Wc2^T, fused update
        // h2 -> A2 cols [512,1024) (next step); final step also -> out (fp32)
        gemm_lstm<<<dim3(NG / BN, BROWS / BM), dim3(256), 0, stream>>>(
            A2, Wc2, Bp2, c2,
            A2, K2, RNN,
            (bf16*)nullptr, 0, 0, 0,
            out, (t == TSTEPS - 1) ? 1 : 0, K2);
    }
}

// Round 3
// 1274.705 us; speedup vs baseline: 1.3361x; 1.0689x over previous
//
#include <hip/hip_runtime.h>
#include <hip/hip_bf16.h>

// Problem constants (from reference): B=64, NCLS=200 -> BN rows = 12800
#define BROWS  12800
#define TSTEPS 8
#define EMB    300
#define EMBP   320          // EMB padded to /32 for MFMA K
#define RNN    512
#define NG     2048         // 4*RNN gate width
#define K1     832          // EMBP + RNN  (layer-1 concat GEMM K), 13*64
#define K2     1024         // RNN + RNN   (layer-2 concat GEMM K), 16*64

typedef short bf16x8 __attribute__((ext_vector_type(8)));   // 8 bf16 in 4 VGPRs (m89-verified operand type)
typedef float f32x4  __attribute__((ext_vector_type(4)));
typedef __hip_bfloat16 bf16;

__device__ __forceinline__ float sigmoidf_(float x) { return 1.f / (1.f + __expf(-x)); }
// exp-based tanh: exact saturation at +-inf, ~ulp-level error vs tanhf, one v_exp
__device__ __forceinline__ float tanhf_(float x)    { return 1.f - 2.f / (__expf(2.f * x) + 1.f); }

// async global->LDS, 16B per lane. HW semantics (m97/m104): LDS dest is
// wave-uniform base + lane*16 — the lptr we pass per-lane must equal exactly
// that, i.e. LDS layout must be contiguous in lane order (no padding).
__device__ __forceinline__ void gl_lds16(const bf16* g, bf16* l) {
    __builtin_amdgcn_global_load_lds(
        (const __attribute__((address_space(1))) void*)g,
        (__attribute__((address_space(3))) void*)l,
        16, 0, 0);
}

// ---------------------------------------------------------------------------
// Weight repack: fp32 -> bf16, K-concatenated row-major [N=2048][K], with the
// GATE-INTERLEAVED row permutation: output row n encodes
//   w = n&15 (unit), g = (n>>4)&3 (gate i,f,g,o), b = n>>6 (unit group)
//   original row = g*512 + b*16 + w
// so each wave's 64-col span = [i|f|g|o] of the same 16 units (epilogue needs
// no cross-lane exchange). Also emits permuted combined biases Bp = bih+bhh.
// ---------------------------------------------------------------------------
__global__ void convert_weights(const float* __restrict__ Wih1, const float* __restrict__ Whh1,
                                const float* __restrict__ Wih2, const float* __restrict__ Whh2,
                                const float* __restrict__ bih1, const float* __restrict__ bhh1,
                                const float* __restrict__ bih2, const float* __restrict__ bhh2,
                                bf16* __restrict__ Wc1, bf16* __restrict__ Wc2,
                                float* __restrict__ Bp1, float* __restrict__ Bp2) {
    int idx = blockIdx.x * 256 + threadIdx.x;
    const int n1 = NG * K1;   // 1,703,936
    const int n2 = NG * K2;   // 2,097,152
    if (idx < n1) {
        int n = idx / K1, k = idx - n * K1;
        int on = ((n >> 4) & 3) * RNN + (n >> 6) * 16 + (n & 15);
        float v = 0.f;
        if (k < EMB)        v = Wih1[on * EMB + k];
        else if (k >= EMBP) v = Whh1[on * RNN + (k - EMBP)];
        Wc1[idx] = __float2bfloat16(v);
    }
    if (idx < n2) {
        int n = idx >> 10, k = idx & (K2 - 1);
        int on = ((n >> 4) & 3) * RNN + (n >> 6) * 16 + (n & 15);
        float v = (k < RNN) ? Wih2[on * RNN + k] : Whh2[on * RNN + (k - RNN)];
        Wc2[idx] = __float2bfloat16(v);
    }
    if (idx < NG) {
        int on = ((idx >> 4) & 3) * RNN + (idx >> 6) * 16 + (idx & 15);
        Bp1[idx] = bih1[on] + bhh1[on];
        Bp2[idx] = bih2[on] + bhh2[on];
    }
}

// ---------------------------------------------------------------------------
// Embedding gather + tanh for one timestep -> x-slot (cols 0..319, pad
// zeroed) of the layer-1 A-concat buffer Ac1 [BROWS][K1].
// ---------------------------------------------------------------------------
__global__ void embed_step(const int* __restrict__ sent, const float* __restrict__ w2v,
                           bf16* __restrict__ Ac1, int t) {
    int row = blockIdx.x;
    int col = threadIdx.x;                 // 0..319
    int id  = sent[row * TSTEPS + t];
    float v = (col < EMB) ? tanhf_(w2v[id * EMB + col]) : 0.f;
    Ac1[(size_t)row * K1 + col] = __float2bfloat16(v);
}

// ---------------------------------------------------------------------------
// Fused GEMM + LSTM cell update.
//   gates[M,2048] = A[M,K] * B[2048,K]^T  (bf16 MFMA 16x16x32, fp32 acc)
// then per (row,unit): c' = sig(f)*c + sig(i)*tanh(g); h = sig(o)*tanh(c').
//
// Staging: global_load_lds width=16 (m97 rung, 1.69x over VGPR round-trip).
// LDS is UNPADDED [128][64] bf16 (lane-order constraint of global_load_lds);
// bank spread comes from an XOR chunk swizzle applied on the GLOBAL side:
//   LDS[row][chunk c] holds global k-chunk (c ^ (row&7))   (chunks of 8 bf16)
// Reader compensates: k-chunk q+kk/8 of row r is at LDS column ((q+kk/8)^(r&7)).
// Global coalescing is preserved (8 lanes permute chunks within one 128B row).
//
// Block 256 thr = 4 waves; tile 128x128; wave = 64x64 = 4x4 MFMA tiles.
// Weight permutation => acc[i][0..3][rr] = gates i,f,g,o of one (row,unit).
// Grid (16,100), bn fastest => concurrent blocks share A row-tiles in L2.
// ---------------------------------------------------------------------------
#define BM 128
#define BN 128
#define BK 64

__global__ __launch_bounds__(256, 4) void gemm_lstm(const bf16* __restrict__ A,
                                                    const bf16* __restrict__ B,
                                                    const float* __restrict__ Bp,
                                                    float* __restrict__ cst,
                                                    bf16* __restrict__ hdst1, int ld1, int off1,
                                                    bf16* __restrict__ hdst2, int ld2, int off2, int en2,
                                                    float* __restrict__ outf, int en_out,
                                                    int K) {
    __shared__ __attribute__((aligned(16))) bf16 sA[BM * BK];   // 16 KB
    __shared__ __attribute__((aligned(16))) bf16 sB[BN * BK];   // 16 KB

    const int tid  = threadIdx.x;
    const int lane = tid & 63;
    const int wave = tid >> 6;
    const int wm   = wave >> 1, wn = wave & 1;
    const int bn   = blockIdx.x;           // 16  (gate-col blocks)
    const int bm   = blockIdx.y;           // 100 (row blocks)

    f32x4 acc[4][4];
#pragma unroll
    for (int i = 0; i < 4; ++i)
#pragma unroll
        for (int j = 0; j < 4; ++j)
#pragma unroll
            for (int r = 0; r < 4; ++r) acc[i][j][r] = 0.f;

    const int r = lane & 15, q = lane >> 4;

    // Per-thread staging geometry (constant across K-blocks):
    // chunk ch = c*256 + tid; row = ch>>3; global k-chunk = (ch&7)^(row&7).
    int srow[4], scol[4];
#pragma unroll
    for (int c = 0; c < 4; ++c) {
        int ch = c * 256 + tid;
        srow[c] = ch >> 3;
        scol[c] = ((ch & 7) ^ (srow[c] & 7)) * 8;
    }
    const bf16* Abase = A + (size_t)(bm * BM) * K;
    const bf16* Bbase = B + (size_t)(bn * BN) * K;

    for (int kb = 0; kb < K; kb += BK) {
#pragma unroll
        for (int c = 0; c < 4; ++c) {
            int ch = c * 256 + tid;
            gl_lds16(Abase + (size_t)srow[c] * K + kb + scol[c], &sA[ch * 8]);
            gl_lds16(Bbase + (size_t)srow[c] * K + kb + scol[c], &sB[ch * 8]);
        }
        __syncthreads();
#pragma unroll
        for (int kk = 0; kk < BK; kk += 32) {
            const int kc = kk >> 3;        // 0 or 4
            bf16x8 af[4], bfr[4];
#pragma unroll
            for (int i = 0; i < 4; ++i)
                af[i] = *(const bf16x8*)(&sA[(wm * 64 + i * 16 + r) * BK + (((q + kc) ^ (r & 7)) * 8)]);
#pragma unroll
            for (int j = 0; j < 4; ++j)
                bfr[j] = *(const bf16x8*)(&sB[(wn * 64 + j * 16 + r) * BK + (((q + kc) ^ (r & 7)) * 8)]);
#pragma unroll
            for (int i = 0; i < 4; ++i)
#pragma unroll
                for (int j = 0; j < 4; ++j)
                    acc[i][j] = __builtin_amdgcn_mfma_f32_16x16x32_bf16(
                        af[i], bfr[j], acc[i][j], 0, 0, 0);
        }
        __syncthreads();
    }

    // ---- fused LSTM epilogue ----
    // C/D mapping (m89/m91-verified): col = lane&15, row = (lane>>4)*4 + reg
    const int colb = bn * BN + wn * 64;           // this wave's first gate col
    const int u    = (2 * bn + wn) * 16 + r;      // global unit index
    const float bi = Bp[colb + r];
    const float bf = Bp[colb + 16 + r];
    const float bg = Bp[colb + 32 + r];
    const float bo = Bp[colb + 48 + r];

#pragma unroll
    for (int i = 0; i < 4; ++i) {
#pragma unroll
        for (int rr = 0; rr < 4; ++rr) {
            int row = bm * BM + wm * 64 + i * 16 + q * 4 + rr;
            size_t cidx = (size_t)row * RNN + u;
            float gi = acc[i][0][rr] + bi;
            float gf = acc[i][1][rr] + bf;
            float gg = acc[i][2][rr] + bg;
            float go = acc[i][3][rr] + bo;
            float cn = sigmoidf_(gf) * cst[cidx] + sigmoidf_(gi) * tanhf_(gg);
            float h  = sigmoidf_(go) * tanhf_(cn);
            cst[cidx] = cn;
            bf16 hb = __float2bfloat16(h);
            hdst1[(size_t)row * ld1 + off1 + u] = hb;
            if (en2)    hdst2[(size_t)row * ld2 + off2 + u] = hb;
            if (en_out) outf[cidx] = h;
        }
    }
}

// ---------------------------------------------------------------------------
// Workspace layout (all 16B-aligned; total 107,560,960 B):
//   c1  fp32 [12800][512]            26,214,400
//   c2  fp32 [12800][512]            26,214,400
//   A2  bf16 [12800][1024]           26,214,400   ([h1|h2] for layer-2 GEMM)
//   Ac1 bf16 [12800][832]            21,299,200   ([x_t(pad)|h1] for layer-1)
//   Wc1 bf16 [2048][832]              3,407,872
//   Wc2 bf16 [2048][1024]             4,194,304
//   Bp1 fp32 [2048]                       8,192
//   Bp2 fp32 [2048]                       8,192
// First 99,942,400 B (c1,c2,A2,Ac1) must be zero at t=0 -> one memsetAsync.
// ---------------------------------------------------------------------------
extern "C" void kernel_launch(void* const* d_in, const int* in_sizes, int n_in,
                              void* d_out, int out_size, void* d_ws, size_t ws_size,
                              hipStream_t stream) {
    (void)in_sizes; (void)n_in; (void)out_size; (void)ws_size;
    const int*   sent = (const int*)d_in[0];
    const float* w2v  = (const float*)d_in[1];
    const float* Wih1 = (const float*)d_in[2];
    const float* Whh1 = (const float*)d_in[3];
    const float* bih1 = (const float*)d_in[4];
    const float* bhh1 = (const float*)d_in[5];
    const float* Wih2 = (const float*)d_in[6];
    const float* Whh2 = (const float*)d_in[7];
    const float* bih2 = (const float*)d_in[8];
    const float* bhh2 = (const float*)d_in[9];
    float* out = (float*)d_out;

    char* ws = (char*)d_ws;
    float* c1  = (float*)(ws);
    float* c2  = (float*)(ws + 26214400);
    bf16*  A2  = (bf16*) (ws + 52428800);
    bf16*  Ac1 = (bf16*) (ws + 78643200);
    bf16*  Wc1 = (bf16*) (ws + 99942400);
    bf16*  Wc2 = (bf16*) (ws + 103350272);
    float* Bp1 = (float*)(ws + 107544576);
    float* Bp2 = (float*)(ws + 107552768);

    // zero h/c state + A-buffers (ws is re-poisoned 0xAA before every call)
    hipMemsetAsync(ws, 0, 99942400, stream);

    convert_weights<<<dim3((NG * K2 + 255) / 256), dim3(256), 0, stream>>>(
        Wih1, Whh1, Wih2, Whh2, bih1, bhh1, bih2, bhh2, Wc1, Wc2, Bp1, Bp2);

    for (int t = 0; t < TSTEPS; ++t) {
        // x_t -> Ac1 cols [0,320); h1(t-1) already sits in cols [320,832)
        embed_step<<<dim3(BROWS), dim3(EMBP), 0, stream>>>(sent, w2v, Ac1, t);

        // layer 1: gates = [x_t|h1] @ Wc1^T, fused update
        // h1 -> Ac1 h-slot (next step) and A2 cols [0,512) (this step)
        gemm_lstm<<<dim3(NG / BN, BROWS / BM), dim3(256), 0, stream>>>(
            Ac1, Wc1, Bp1, c1,
            Ac1, K1, EMBP,
            A2,  K2, 0, 1,
            (float*)nullptr, 0, K1);

        // layer 2: gates = [h1|h2] @ Wc2^T, fused update
        // h2 -> A2 cols [512,1024) (next step); final step also -> out (fp32)
        gemm_lstm<<<dim3(NG / BN, BROWS / BM), dim3(256), 0, stream>>>(
            A2, Wc2, Bp2, c2,
            A2, K2, RNN,
            (bf16*)nullptr, 0, 0, 0,
            out, (t == TSTEPS - 1) ? 1 : 0, K2);
    }
}